// Round 1
// baseline (50.122 us; speedup 1.0000x reference)
//
#include <hip/hip_runtime.h>

#define EMBED_DIM 64
#define MAX_NB 50
#define WAVES_PER_BLOCK 4

__global__ __launch_bounds__(WAVES_PER_BLOCK * 64)
void social_agg_kernel(const int* __restrict__ nodes,
                       const int* __restrict__ u_u,
                       const float* __restrict__ u_u_l,
                       const float* __restrict__ emb,
                       float* __restrict__ out,
                       int batch)
{
    const int lane = threadIdx.x & 63;
    const int wave = threadIdx.x >> 6;
    const int row  = blockIdx.x * WAVES_PER_BLOCK + wave;
    if (row >= batch) return;

    const int node = nodes[row];              // broadcast load (same addr all lanes)
    const float Na = u_u_l[node];

    // Lanes 0..49 each fetch one neighbor id + its weight.
    int   nb = 0;
    float w  = 0.0f;
    if (lane < MAX_NB) {
        nb = u_u[node * MAX_NB + lane];       // coalesced 200B row read
        const float Nb   = u_u_l[nb];         // 400KB table -> cache-hot
        const float prod = Na * Nb;
        // 1/(sqrt(Na)*sqrt(Nb)) with isinf->0 mask == 0 whenever Na==0 or Nb==0
        w = (prod > 0.0f) ? rsqrtf(prod) : 0.0f;
    }

    float acc = 0.0f;
    #pragma unroll
    for (int k = 0; k < MAX_NB; ++k) {
        const float wk = __shfl(w, k);        // wave-uniform after shfl
        if (wk != 0.0f) {                     // uniform branch: skip dead gathers
            const int nbk = __shfl(nb, k);
            acc += wk * emb[(long)nbk * EMBED_DIM + lane];  // 256B coalesced gather
        }
    }

    out[(long)row * EMBED_DIM + lane] = acc;
}

extern "C" void kernel_launch(void* const* d_in, const int* in_sizes, int n_in,
                              void* d_out, int out_size, void* d_ws, size_t ws_size,
                              hipStream_t stream) {
    const int*   nodes = (const int*)d_in[0];
    const int*   u_u   = (const int*)d_in[1];
    const float* u_u_l = (const float*)d_in[2];
    const float* emb   = (const float*)d_in[3];
    float*       out   = (float*)d_out;

    const int batch  = in_sizes[0];
    const int blocks = (batch + WAVES_PER_BLOCK - 1) / WAVES_PER_BLOCK;
    social_agg_kernel<<<blocks, WAVES_PER_BLOCK * 64, 0, stream>>>(
        nodes, u_u, u_u_l, emb, out, batch);
}

// Round 2
// 35.469 us; speedup vs baseline: 1.4131x; 1.4131x over previous
//
#include <hip/hip_runtime.h>

#define D 64
#define K 50
#define ROWS_PER_BLOCK 16   // 4 waves * 4 rows per wave
#define THREADS 256

__global__ __launch_bounds__(THREADS)
void social_agg_kernel(const int* __restrict__ nodes,
                       const int* __restrict__ u_u,
                       const float* __restrict__ u_u_l,
                       const float* __restrict__ emb,
                       float* __restrict__ out,
                       int batch)
{
    // x = neighbor id, y = bitcast(weight); one ds_read_b64 per (row,k)
    __shared__ uint2 nw[ROWS_PER_BLOCK][K];

    const int base = blockIdx.x * ROWS_PER_BLOCK;

    // Phase 1: compute all 16*50 (neighbor, weight) pairs block-cooperatively.
    for (int p = threadIdx.x; p < ROWS_PER_BLOCK * K; p += THREADS) {
        const int r   = p / K;
        const int k   = p - r * K;
        const int row = base + r;
        int nb = 0; float w = 0.0f;
        if (row < batch) {
            const int   node = nodes[row];
            const float Na   = u_u_l[node];
            nb = u_u[node * K + k];                 // contiguous within a row
            const float Nb   = u_u_l[nb];           // 400 KB table, cache-hot
            const float prod = Na * Nb;
            // 1/(sqrt(Na)*sqrt(Nb)) with isinf->0 == 0 whenever Na==0 or Nb==0
            w = (prod > 0.0f) ? rsqrtf(prod) : 0.0f;
        }
        nw[r][k] = make_uint2((unsigned)nb, __float_as_uint(w));
    }
    __syncthreads();

    // Phase 2: 16-lane group per row, float4 per lane -> 1024 B per wave gather.
    const int lane = threadIdx.x & 63;
    const int wave = threadIdx.x >> 6;
    const int g    = lane >> 4;                     // group 0..3 within wave
    const int sub  = lane & 15;                     // dim quarter
    const int r    = wave * 4 + g;
    const int row  = base + r;

    float4 acc = make_float4(0.f, 0.f, 0.f, 0.f);
    #pragma unroll
    for (int k = 0; k < K; ++k) {
        const uint2  e  = nw[r][k];                 // broadcast within group
        const float  wk = __uint_as_float(e.y);
        const float4 v  = *(const float4*)(emb + (size_t)e.x * D + sub * 4);
        acc.x += wk * v.x;
        acc.y += wk * v.y;
        acc.z += wk * v.z;
        acc.w += wk * v.w;
    }

    if (row < batch)
        *(float4*)(out + (size_t)row * D + sub * 4) = acc;   // wave: 1 KiB contiguous
}

extern "C" void kernel_launch(void* const* d_in, const int* in_sizes, int n_in,
                              void* d_out, int out_size, void* d_ws, size_t ws_size,
                              hipStream_t stream) {
    const int*   nodes = (const int*)d_in[0];
    const int*   u_u   = (const int*)d_in[1];
    const float* u_u_l = (const float*)d_in[2];
    const float* emb   = (const float*)d_in[3];
    float*       out   = (float*)d_out;

    const int batch  = in_sizes[0];
    const int blocks = (batch + ROWS_PER_BLOCK - 1) / ROWS_PER_BLOCK;
    social_agg_kernel<<<blocks, THREADS, 0, stream>>>(
        nodes, u_u, u_u_l, emb, out, batch);
}

// Round 3
// 34.200 us; speedup vs baseline: 1.4655x; 1.0371x over previous
//
#include <hip/hip_runtime.h>

#define D 64
#define K 50
#define KK 4                  // K-slots processed in parallel per wave (4 groups of 16 lanes)
#define KPAD (KK * 13)        // 52: K rounded up to multiple of KK
#define ROWS_PER_BLOCK 4      // one wave per row
#define THREADS 256

__global__ __launch_bounds__(THREADS)
void social_agg_kernel(const int* __restrict__ nodes,
                       const int* __restrict__ u_u,
                       const float* __restrict__ u_u_l,
                       const float* __restrict__ emb,
                       float* __restrict__ out,
                       int batch)
{
    // x = neighbor id, y = bitcast(weight)
    __shared__ uint2 nw[ROWS_PER_BLOCK][KPAD];

    const int base = blockIdx.x * ROWS_PER_BLOCK;

    // Phase 1: fill all 4*52 (neighbor, weight) slots; one slot per thread.
    {
        const int p = threadIdx.x;
        if (p < ROWS_PER_BLOCK * KPAD) {
            const int r   = p / KPAD;
            const int k   = p - r * KPAD;
            const int row = base + r;
            int nb = 0; float w = 0.0f;
            if (row < batch && k < K) {
                const int   node = nodes[row];
                const float Na   = u_u_l[node];
                nb = u_u[node * K + k];              // coalesced row segment
                const float Nb   = u_u_l[nb];        // 400 KB table, cache-hot
                const float prod = Na * Nb;
                // 1/(sqrt(Na)*sqrt(Nb)) with isinf->0 == 0 when Na==0 or Nb==0
                w = (prod > 0.0f) ? rsqrtf(prod) : 0.0f;
            }
            nw[r][k] = make_uint2((unsigned)nb, __float_as_uint(w));
        }
    }
    __syncthreads();

    // Phase 2: one wave per row; group kk = lane>>4 handles k = 4i+kk.
    const int wave = threadIdx.x >> 6;
    const int lane = threadIdx.x & 63;
    const int kk   = lane >> 4;
    const int sub  = lane & 15;
    const int row  = base + wave;

    float4 acc = make_float4(0.f, 0.f, 0.f, 0.f);
    #pragma unroll
    for (int i = 0; i < KPAD / KK; ++i) {
        const uint2  e  = nw[wave][i * KK + kk];     // LDS broadcast per group
        const float  wk = __uint_as_float(e.y);
        const float4 v  = *(const float4*)(emb + (size_t)e.x * D + sub * 4);
        acc.x += wk * v.x;
        acc.y += wk * v.y;
        acc.z += wk * v.z;
        acc.w += wk * v.w;
    }

    // Reduce the 4 K-groups: lanes {sub, 16+sub, 32+sub, 48+sub} hold partials.
    #pragma unroll
    for (int off = 16; off <= 32; off <<= 1) {
        acc.x += __shfl_xor(acc.x, off);
        acc.y += __shfl_xor(acc.y, off);
        acc.z += __shfl_xor(acc.z, off);
        acc.w += __shfl_xor(acc.w, off);
    }

    if (row < batch && kk == 0)
        *(float4*)(out + (size_t)row * D + sub * 4) = acc;  // 256 B per wave
}

extern "C" void kernel_launch(void* const* d_in, const int* in_sizes, int n_in,
                              void* d_out, int out_size, void* d_ws, size_t ws_size,
                              hipStream_t stream) {
    const int*   nodes = (const int*)d_in[0];
    const int*   u_u   = (const int*)d_in[1];
    const float* u_u_l = (const float*)d_in[2];
    const float* emb   = (const float*)d_in[3];
    float*       out   = (float*)d_out;

    const int batch  = in_sizes[0];
    const int blocks = (batch + ROWS_PER_BLOCK - 1) / ROWS_PER_BLOCK;
    social_agg_kernel<<<blocks, THREADS, 0, stream>>>(
        nodes, u_u, u_u_l, emb, out, batch);
}

// Round 4
// 29.203 us; speedup vs baseline: 1.7163x; 1.1711x over previous
//
#include <hip/hip_runtime.h>

#define D 64
#define K 50
#define KK 4                  // K-groups per wave (4 x 16 lanes)
#define KPAD (KK * 13)        // 52
#define ROWS_PER_BLOCK 4      // one wave per output row
#define THREADS 256

// ---------- prologue: emb fp32 -> bf16 (RNE) into ws; rtab[u] = deg>0 ? rsqrt(deg) : 0
__global__ __launch_bounds__(THREADS)
void prep_kernel(const float* __restrict__ emb, const float* __restrict__ deg,
                 unsigned* __restrict__ emb16, float* __restrict__ rtab,
                 int npack4, int nuser)
{
    const int p = blockIdx.x * THREADS + threadIdx.x;
    if (p < npack4) {
        const float4 f = ((const float4*)emb)[p];
        unsigned a = __float_as_uint(f.x), b = __float_as_uint(f.y);
        unsigned c = __float_as_uint(f.z), d = __float_as_uint(f.w);
        a = (a + 0x7FFFu + ((a >> 16) & 1u)) >> 16;   // RNE bf16
        b = (b + 0x7FFFu + ((b >> 16) & 1u)) >> 16;
        c = (c + 0x7FFFu + ((c >> 16) & 1u)) >> 16;
        d = (d + 0x7FFFu + ((d >> 16) & 1u)) >> 16;
        ((uint2*)emb16)[p] = make_uint2(a | (b << 16), c | (d << 16));
    }
    if (p < nuser) {
        const float n = deg[p];
        rtab[p] = (n > 0.0f) ? rsqrtf(n) : 0.0f;
    }
}

// ---------- main: bf16 gather, 16 lanes x 8B per neighbor row, 4 K-groups/wave
__global__ __launch_bounds__(THREADS)
void social_agg_bf16(const int* __restrict__ nodes,
                     const int* __restrict__ u_u,
                     const float* __restrict__ rtab,
                     const unsigned* __restrict__ emb16,
                     float* __restrict__ out,
                     int batch)
{
    __shared__ uint2 nw[ROWS_PER_BLOCK][KPAD];   // x = neighbor id, y = bitcast(w)
    const int base = blockIdx.x * ROWS_PER_BLOCK;

    const int p = threadIdx.x;
    if (p < ROWS_PER_BLOCK * KPAD) {
        const int r   = p / KPAD;
        const int k   = p - r * KPAD;
        const int row = base + r;
        int nb = 0; float w = 0.0f;
        if (row < batch && k < K) {
            const int node = nodes[row];
            nb = u_u[node * K + k];
            w  = rtab[node] * rtab[nb];          // == 1/(sqrt(Na)sqrt(Nb)), 0 if either deg==0
        }
        nw[r][k] = make_uint2((unsigned)nb, __float_as_uint(w));
    }
    __syncthreads();

    const int wave = threadIdx.x >> 6;
    const int lane = threadIdx.x & 63;
    const int kk   = lane >> 4;
    const int sub  = lane & 15;
    const int row  = base + wave;

    float a0 = 0.f, a1 = 0.f, a2 = 0.f, a3 = 0.f;
    #pragma unroll
    for (int i = 0; i < KPAD / KK; ++i) {
        const uint2 e  = nw[wave][i * KK + kk];
        const float wk = __uint_as_float(e.y);
        const uint2 v  = *(const uint2*)(emb16 + (size_t)e.x * (D / 2) + sub * 2);
        a0 += wk * __uint_as_float(v.x << 16);
        a1 += wk * __uint_as_float(v.x & 0xFFFF0000u);
        a2 += wk * __uint_as_float(v.y << 16);
        a3 += wk * __uint_as_float(v.y & 0xFFFF0000u);
    }

    #pragma unroll
    for (int off = 16; off <= 32; off <<= 1) {
        a0 += __shfl_xor(a0, off);
        a1 += __shfl_xor(a1, off);
        a2 += __shfl_xor(a2, off);
        a3 += __shfl_xor(a3, off);
    }

    if (row < batch && kk == 0) {
        const float4 o = make_float4(a0, a1, a2, a3);
        *(float4*)(out + (size_t)row * D + sub * 4) = o;
    }
}

// ---------- fallback (fp32 path, R2 kernel) if workspace is too small
__global__ __launch_bounds__(THREADS)
void social_agg_f32(const int* __restrict__ nodes,
                    const int* __restrict__ u_u,
                    const float* __restrict__ u_u_l,
                    const float* __restrict__ emb,
                    float* __restrict__ out,
                    int batch)
{
    __shared__ uint2 nw[ROWS_PER_BLOCK][KPAD];
    const int base = blockIdx.x * ROWS_PER_BLOCK;
    const int p = threadIdx.x;
    if (p < ROWS_PER_BLOCK * KPAD) {
        const int r = p / KPAD, k = p - r * KPAD, row = base + r;
        int nb = 0; float w = 0.0f;
        if (row < batch && k < K) {
            const int node = nodes[row];
            const float Na = u_u_l[node];
            nb = u_u[node * K + k];
            const float prod = Na * u_u_l[nb];
            w = (prod > 0.0f) ? rsqrtf(prod) : 0.0f;
        }
        nw[r][k] = make_uint2((unsigned)nb, __float_as_uint(w));
    }
    __syncthreads();
    const int wave = threadIdx.x >> 6, lane = threadIdx.x & 63;
    const int kk = lane >> 4, sub = lane & 15, row = base + wave;
    float4 acc = make_float4(0.f, 0.f, 0.f, 0.f);
    #pragma unroll
    for (int i = 0; i < KPAD / KK; ++i) {
        const uint2 e = nw[wave][i * KK + kk];
        const float wk = __uint_as_float(e.y);
        const float4 v = *(const float4*)(emb + (size_t)e.x * D + sub * 4);
        acc.x += wk * v.x; acc.y += wk * v.y; acc.z += wk * v.z; acc.w += wk * v.w;
    }
    #pragma unroll
    for (int off = 16; off <= 32; off <<= 1) {
        acc.x += __shfl_xor(acc.x, off);
        acc.y += __shfl_xor(acc.y, off);
        acc.z += __shfl_xor(acc.z, off);
        acc.w += __shfl_xor(acc.w, off);
    }
    if (row < batch && kk == 0)
        *(float4*)(out + (size_t)row * D + sub * 4) = acc;
}

extern "C" void kernel_launch(void* const* d_in, const int* in_sizes, int n_in,
                              void* d_out, int out_size, void* d_ws, size_t ws_size,
                              hipStream_t stream) {
    const int*   nodes = (const int*)d_in[0];
    const int*   u_u   = (const int*)d_in[1];
    const float* u_u_l = (const float*)d_in[2];
    const float* emb   = (const float*)d_in[3];
    float*       out   = (float*)d_out;

    const int batch  = in_sizes[0];
    const int nuser  = in_sizes[1] / K;                  // N_USERS
    const int blocks = (batch + ROWS_PER_BLOCK - 1) / ROWS_PER_BLOCK;

    const size_t emb16_bytes = (size_t)nuser * D * 2;    // bf16 table
    const size_t rtab_bytes  = (size_t)nuser * 4;
    if (ws_size >= emb16_bytes + rtab_bytes) {
        unsigned* emb16 = (unsigned*)d_ws;
        float*    rtab  = (float*)((char*)d_ws + emb16_bytes);
        const int npack4 = nuser * D / 4;                // float4 packs
        const int pblocks = (npack4 + THREADS - 1) / THREADS;
        prep_kernel<<<pblocks, THREADS, 0, stream>>>(emb, u_u_l, emb16, rtab,
                                                     npack4, nuser);
        social_agg_bf16<<<blocks, THREADS, 0, stream>>>(nodes, u_u, rtab, emb16,
                                                        out, batch);
    } else {
        social_agg_f32<<<blocks, THREADS, 0, stream>>>(nodes, u_u, u_u_l, emb,
                                                       out, batch);
    }
}